// Round 10
// baseline (286.772 us; speedup 1.0000x reference)
//
#include <hip/hip_runtime.h>
#include <hip/hip_bf16.h>
#include <stdint.h>

// ---------------------------------------------------------------------------
// SparseLinear: y[B,N] = x[B,M] @ W^T + bias, W given as CSR.
// R13: rotate the read/MFMA pipeline ACROSS the tile barrier.
//   R12 post-mortem: spill-free (WRITE 66MB, VGPR 96) but 132 us, MfmaUtil
//   43%. Timeline: [MFMA k0 || reads k1] + [MFMA k1, idle LDS] + [exposed
//   reads k0 at tile head] = 620+620+570 ~ 2475 cyc. Only one of two read
//   bursts overlapped; reads k0(t) can only hide under MFMA k1(t-1).
//   Fix: mid-tile barrier + fragment set carried across tiles:
//     step1: { reads S1=(t,k1) from cur ; MFMA k0(t) with S0 }
//     step2: s_waitcnt vmcnt(0) lgkmcnt(0); s_barrier
//            // lgkm0 -> every wave's reads of cur complete => stage into
//            // cur below is STRICTLY WAR-safe; vm0 retires stage(t+1)
//            // (issued ~1 tile ago > HBM latency); barrier publishes nxt.
//     step3: { stage(t+2) into cur-space ; reads S0'=(t+1,k0) from nxt ;
//              MFMA k1(t) with S1 }
//   Every MFMA cluster has a read burst under it. Liveness: 2 frag sets
//   (64 VGPR) + acc (64 AGPR) -- same budget as spill-free R12.
//   FP order per output element unchanged (k ascending) -> absmax 0.03125.
//   Geometry unchanged from R12: 8 waves, wave tile 64x64, block 128x256,
//   BK=64, LDS 96 KiB, grid 512, bijective XCD swizzle.
// ---------------------------------------------------------------------------

#define B_DIM 4096
#define M_DIM 4096
#define N_DIM 4096
#define NNZ_ROW 819

typedef __attribute__((ext_vector_type(8))) __bf16 bf16x8;
typedef __attribute__((ext_vector_type(4))) float f32x4;

__device__ __forceinline__ unsigned short f32_to_bf16(float f) {
    union { float f; unsigned int u; } v;
    v.f = f;
    unsigned int r = v.u + 0x7FFFu + ((v.u >> 16) & 1u);  // RNE
    return (unsigned short)(r >> 16);
}

__device__ __forceinline__ void load_lds16(const void* g, void* l) {
    __builtin_amdgcn_global_load_lds(
        (const __attribute__((address_space(1))) void*)g,
        (__attribute__((address_space(3))) void*)l,
        16, 0, 0);
}

// ---- merged prologue: densify W rows (blocks 0..4095) + X fp32->bf16
//      (blocks 4096..12287, 8 floats/thread, exact grid) --------------------
__global__ __launch_bounds__(256) void prep(
    const float* __restrict__ wval,
    const int* __restrict__ cols,
    unsigned short* __restrict__ wb,
    const float4* __restrict__ x,
    uint4* __restrict__ xb) {
    const int tid = threadIdx.x;
    if (blockIdx.x >= N_DIM) {
        const int i = (blockIdx.x - N_DIM) * 256 + tid;   // 0 .. 2M-1, exact
        const float4 a = x[2 * i];
        const float4 b = x[2 * i + 1];
        union { ushort ush[8]; uint4 u4; } o;
        o.ush[0] = f32_to_bf16(a.x); o.ush[1] = f32_to_bf16(a.y);
        o.ush[2] = f32_to_bf16(a.z); o.ush[3] = f32_to_bf16(a.w);
        o.ush[4] = f32_to_bf16(b.x); o.ush[5] = f32_to_bf16(b.y);
        o.ush[6] = f32_to_bf16(b.z); o.ush[7] = f32_to_bf16(b.w);
        xb[i] = o.u4;
        return;
    }
    __shared__ __attribute__((aligned(16))) unsigned short row_s[M_DIM];  // 8 KB
    const int row = blockIdx.x;
    uint4* rs4 = (uint4*)row_s;
    rs4[tid]       = make_uint4(0u, 0u, 0u, 0u);
    rs4[tid + 256] = make_uint4(0u, 0u, 0u, 0u);
    __syncthreads();
    const size_t base = (size_t)row * NNZ_ROW;
    for (int j = tid; j < NNZ_ROW; j += 256) {
        const int c = cols[base + j];
        row_s[c] = f32_to_bf16(wval[base + j]);
    }
    __syncthreads();
    uint4* dst = (uint4*)(wb + (size_t)row * M_DIM);
    dst[tid]       = rs4[tid];
    dst[tid + 256] = rs4[tid + 256];
}

// ---------------------------------------------------------------------------
// Stage one 128-row half-tile (128 rows x 64 k, bf16) for K-offset kt.
// 8 waves: wave w writes segments {2w, 2w+1} (8 rows, 1024 B each) at
// LINEAR dest (base + lane*16). Lane's slot: row r = seg*8 + (l>>3),
// chunk' = l&7; LDS(r,c') holds global chunk c' ^ (r&7) = (l&7) ^ (l>>3).
// ---------------------------------------------------------------------------
__device__ __forceinline__ void stage_half(
    const unsigned short* __restrict__ src,
    int grow0, int kt, unsigned short* dst, int w, int l) {
#pragma unroll
    for (int j = 0; j < 2; ++j) {
        const int seg = w * 2 + j;
        const int r   = seg * 8 + (l >> 3);
        const int cg  = (l >> 3) ^ (l & 7);
        load_lds16(src + (size_t)(grow0 + r) * M_DIM + kt + cg * 8,
                   dst + seg * 512);
    }
}

#define MFMA_STEP(ASET, BSET)                                                  \
    __builtin_amdgcn_s_setprio(1);                                             \
    _Pragma("unroll")                                                          \
    for (int mf = 0; mf < 4; ++mf)                                             \
        _Pragma("unroll")                                                      \
        for (int nf = 0; nf < 4; ++nf)                                         \
            acc[mf][nf] = __builtin_amdgcn_mfma_f32_16x16x32_bf16(             \
                ASET[mf], BSET[nf], acc[mf][nf], 0, 0, 0);                     \
    __builtin_amdgcn_s_setprio(0);

// ---------------------------------------------------------------------------
// One K-tile, rotated pipeline (see header). S0 = (ac,bc) carried in from
// the previous tile; on exit holds frags(t+1, k0) read from nxt.
// Fragment addressing (proven R7): row = wavebase + mf*16 + l15, chunk
// c = KS*4 + (l>>4), stored at chunk' = c ^ (row&7) = c ^ (l&7).
// ---------------------------------------------------------------------------
__device__ __forceinline__ void ktile(
    unsigned short* curA, unsigned short* curB,          // consumed + stage tgt
    const unsigned short* nxtA, const unsigned short* nxtB,
    const unsigned short* __restrict__ Xb, const unsigned short* __restrict__ Wb,
    int bm0, int bn0, int kstage, bool do_stage, bool do_next,
    int wr, int wc, int w, int l,
    bf16x8 (&ac)[4], bf16x8 (&bc)[4], f32x4 (&acc)[4][4])
{
    const int l15 = l & 15;
    const int lg  = l >> 4;
    const int lx  = l & 7;
    const int ck0 = (lg ^ lx) << 3;          // k-chunk 0 ushort offset
    const int ck1 = ((4 + lg) ^ lx) << 3;    // k-chunk 1

    const unsigned short* A0c = curA + (wr * 64 + l15) * 64;
    const unsigned short* B0c = curB + (wc * 64 + l15) * 64;

    // ---- step 1: issue reads S1 = (t,k1) from cur; MFMA k0 with S0 ----
    bf16x8 an[4], bn[4];
#pragma unroll
    for (int mf = 0; mf < 4; ++mf)
        an[mf] = *(const bf16x8*)(A0c + mf * 1024 + ck1);
#pragma unroll
    for (int nf = 0; nf < 4; ++nf)
        bn[nf] = *(const bf16x8*)(B0c + nf * 1024 + ck1);
    MFMA_STEP(ac, bc)
    __builtin_amdgcn_sched_barrier(0);

    // ---- step 2: strict sync point ----
    // lgkmcnt(0): every wave's reads of cur are complete -> staging into cur
    // below is WAR-safe. vmcnt(0): stage(t+1) (issued ~1 tile ago) landed.
    // barrier: publish nxt to all waves.
    __builtin_amdgcn_s_waitcnt(0x0070);   // vmcnt(0) + lgkmcnt(0)
    __builtin_amdgcn_s_barrier();
    __builtin_amdgcn_sched_barrier(0);

    // ---- step 3: stage(t+2) into cur-space; reads S0'=(t+1,k0) from nxt;
    //              MFMA k1 with S1 (already complete -- no wait needed) ----
    if (do_stage) {
        stage_half(Xb, bm0,       kstage, curA, w, l);        // A (128 rows)
        stage_half(Wb, bn0,       kstage, curB, w, l);        // B rows 0-127
        stage_half(Wb, bn0 + 128, kstage, curB + 8192, w, l); // B rows 128-255
    }
    if (do_next) {
        const unsigned short* A0n = nxtA + (wr * 64 + l15) * 64;
        const unsigned short* B0n = nxtB + (wc * 64 + l15) * 64;
#pragma unroll
        for (int mf = 0; mf < 4; ++mf)
            ac[mf] = *(const bf16x8*)(A0n + mf * 1024 + ck0);
#pragma unroll
        for (int nf = 0; nf < 4; ++nf)
            bc[nf] = *(const bf16x8*)(B0n + nf * 1024 + ck0);
    }
    MFMA_STEP(an, bn)
    __builtin_amdgcn_sched_barrier(0);
}

// ---- main GEMM: C[b,n] = sum_k Xb[b,k]*Wb[n,k] + bias[n] -------------------
__global__ __launch_bounds__(512, 2) void gemm_bt_bias(
    const unsigned short* __restrict__ Xb,   // [B][M] bf16 bits
    const unsigned short* __restrict__ Wb,   // [N][M] bf16 bits
    const float* __restrict__ bias,          // [N]
    float* __restrict__ out)                 // [B][N]
{
    // A: 128x64, B: 256x64, double-buffered = 96 KiB total
    __shared__ __attribute__((aligned(16))) unsigned short As0[8192];
    __shared__ __attribute__((aligned(16))) unsigned short Bs0[16384];
    __shared__ __attribute__((aligned(16))) unsigned short As1[8192];
    __shared__ __attribute__((aligned(16))) unsigned short Bs1[16384];

    const int tid = threadIdx.x;
    const int w   = tid >> 6;     // wave 0..7
    const int l   = tid & 63;
    const int wr  = w >> 2;       // 0..1  (64-row M slice)
    const int wc  = w & 3;        // 0..3  (64-col N slice)

    // bijective XCD swizzle: 512 blocks = 8 XCDs x 64 contiguous
    const int wg  = blockIdx.y * 16 + blockIdx.x;     // 0..511
    const int idx = ((wg & 7) << 6) | (wg >> 3);      // xcd*64 + j
    const int bm0 = (idx >> 4) * 128;   // batch rows (32 m-tiles)
    const int bn0 = (idx & 15) * 256;   // N cols (16 n-tiles)

    f32x4 acc[4][4];
#pragma unroll
    for (int a = 0; a < 4; ++a)
#pragma unroll
        for (int b = 0; b < 4; ++b) acc[a][b] = (f32x4)0.0f;

    const int l15 = l & 15;
    const int lg  = l >> 4;
    const int lx  = l & 7;
    const int ck0 = (lg ^ lx) << 3;

    // ---- prologue: stage tiles 0 and 1; read S0 = frags(0, k0) ----
    stage_half(Xb, bm0,       0,  As0,        w, l);
    stage_half(Wb, bn0,       0,  Bs0,        w, l);
    stage_half(Wb, bn0 + 128, 0,  Bs0 + 8192, w, l);
    stage_half(Xb, bm0,       64, As1,        w, l);
    stage_half(Wb, bn0,       64, Bs1,        w, l);
    stage_half(Wb, bn0 + 128, 64, Bs1 + 8192, w, l);
    __builtin_amdgcn_s_waitcnt(0x0F70);   // vmcnt(0), cold start
    __builtin_amdgcn_s_barrier();

    bf16x8 ac_[4], bc_[4];
    {
        const unsigned short* A0 = As0 + (wr * 64 + l15) * 64;
        const unsigned short* B0 = Bs0 + (wc * 64 + l15) * 64;
#pragma unroll
        for (int mf = 0; mf < 4; ++mf)
            ac_[mf] = *(const bf16x8*)(A0 + mf * 1024 + ck0);
#pragma unroll
        for (int nf = 0; nf < 4; ++nf)
            bc_[nf] = *(const bf16x8*)(B0 + nf * 1024 + ck0);
    }
    __builtin_amdgcn_sched_barrier(0);

    // ---- main loop: 2 K-tiles per iteration (buffer ping-pong) ----
    // Tile t stages tile t+2 (same buffer space) at k = (t+2)*64.
#pragma unroll 1
    for (int t = 0; t < 64; t += 2) {
        ktile(As0, Bs0, As1, Bs1, Xb, Wb, bm0, bn0,
              (t + 2) * 64, t + 2 < 64, true,
              wr, wc, w, l, ac_, bc_, acc);
        ktile(As1, Bs1, As0, Bs0, Xb, Wb, bm0, bn0,
              (t + 3) * 64, t + 3 < 64, t + 1 < 63,
              wr, wc, w, l, ac_, bc_, acc);
    }

    // ---- epilogue: D elem r of acc -> row = (l>>4)*4+r, col = l&15 ----
#pragma unroll
    for (int nf = 0; nf < 4; ++nf) {
        const int col = bn0 + wc * 64 + nf * 16 + l15;
        const float bv = bias[col];
#pragma unroll
        for (int mf = 0; mf < 4; ++mf) {
            const int row0 = bm0 + wr * 64 + mf * 16 + lg * 4;
#pragma unroll
            for (int r = 0; r < 4; ++r)
                out[(size_t)(row0 + r) * N_DIM + col] = acc[mf][nf][r] + bv;
        }
    }
}

// ---------------------------------------------------------------------------

extern "C" void kernel_launch(void* const* d_in, const int* in_sizes, int n_in,
                              void* d_out, int out_size, void* d_ws, size_t ws_size,
                              hipStream_t stream) {
    const float* x       = (const float*)d_in[0];
    const float* wval    = (const float*)d_in[1];
    const float* bias    = (const float*)d_in[2];
    const int*   cols    = (const int*)d_in[4];
    float* out = (float*)d_out;

    // workspace: Wb [N*M bf16] (32 MiB) | Xb [B*M bf16] (32 MiB)
    unsigned short* Wb = (unsigned short*)d_ws;
    unsigned short* Xb = Wb + (size_t)N_DIM * M_DIM;

    // merged prologue: 4096 densify blocks + 8192 cvt blocks
    prep<<<dim3(N_DIM + (B_DIM * M_DIM) / 8 / 256), dim3(256), 0, stream>>>(
        wval, cols, Wb, (const float4*)x, (uint4*)Xb);
    // grid: x = N tiles (16 x 256), y = M tiles (32 x 128) -> 512 blocks
    gemm_bt_bias<<<dim3(N_DIM / 256, B_DIM / 128), dim3(512), 0, stream>>>(
        Xb, Wb, bias, out);
}

// Round 11
// 262.114 us; speedup vs baseline: 1.0941x; 1.0941x over previous
//
#include <hip/hip_runtime.h>
#include <hip/hip_bf16.h>
#include <stdint.h>

// ---------------------------------------------------------------------------
// SparseLinear: y[B,N] = x[B,M] @ W^T + bias, W given as CSR.
// R14: m201-faithful phase loop -- within-phase serial, cross-wave overlap.
//   R7..R13 ledger: four schedules, all 130-143 us, MfmaUtil 40-45% --
//   within-wave ILP either spills (R8/R10: acc=128 + lookahead > budget)
//   or serializes (R9/R12/R13). Reference m201 (same chip/shape, plain
//   HIP) = 88 us with the SIMPLE structure: reads -> barrier -> MFMA ->
//   barrier, overlap coming from wave drift + setprio, NOT from
//   within-wave pipelining. My R7 was closest (143 us) but carried
//   per-phase sched_barrier(0) (m141: order-pinning regression) and
//   mid-phase vmcnt churn. R14 = R7 geometry, stripped to m201 form:
//   - 256^2 block, 8 waves 2Mx4N, wave tile 128x64, acc=128 AGPR, BK=64.
//   - Phase (MA,KS) in (0,0),(1,0),(0,1),(1,1): reads 8/4/8/4 (B persists
//     across the MA pair), stages 4/2/2/0, ONE vmcnt(0) at ph4 (newest
//     outstanding stage >= 1 phase old ~ counted wait), barrier, setprio+
//     16 MFMA+setprio, barrier. NO sched_barrier, NO other waits (compiler
//     emits precise counted lgkmcnt for plain C++ ds reads).
//   - Liveness: one frag set at a time (+16 B-persist): ~184 regs, no
//     spill at 2 waves/SIMD.
//   WAR: stage(t+1)->nxt issues after t-1 ph4 end-barrier (all waves'
//   reads of nxt are in regs by then). RAW: ph4 per-wave vmcnt(0) + mid
//   barrier publishes all halves before t+1 ph1 reads. FP order per output
//   element k-ascending -> absmax 0.03125 as all rounds.
// ---------------------------------------------------------------------------

#define B_DIM 4096
#define M_DIM 4096
#define N_DIM 4096
#define NNZ_ROW 819

typedef __attribute__((ext_vector_type(8))) __bf16 bf16x8;
typedef __attribute__((ext_vector_type(4))) float f32x4;

__device__ __forceinline__ unsigned short f32_to_bf16(float f) {
    union { float f; unsigned int u; } v;
    v.f = f;
    unsigned int r = v.u + 0x7FFFu + ((v.u >> 16) & 1u);  // RNE
    return (unsigned short)(r >> 16);
}

__device__ __forceinline__ void load_lds16(const void* g, void* l) {
    __builtin_amdgcn_global_load_lds(
        (const __attribute__((address_space(1))) void*)g,
        (__attribute__((address_space(3))) void*)l,
        16, 0, 0);
}

// ---- merged prologue: densify W rows (blocks 0..4095) + X fp32->bf16
//      (blocks 4096..12287, 8 floats/thread, exact grid) --------------------
__global__ __launch_bounds__(256) void prep(
    const float* __restrict__ wval,
    const int* __restrict__ cols,
    unsigned short* __restrict__ wb,
    const float4* __restrict__ x,
    uint4* __restrict__ xb) {
    const int tid = threadIdx.x;
    if (blockIdx.x >= N_DIM) {
        const int i = (blockIdx.x - N_DIM) * 256 + tid;   // 0 .. 2M-1, exact
        const float4 a = x[2 * i];
        const float4 b = x[2 * i + 1];
        union { ushort ush[8]; uint4 u4; } o;
        o.ush[0] = f32_to_bf16(a.x); o.ush[1] = f32_to_bf16(a.y);
        o.ush[2] = f32_to_bf16(a.z); o.ush[3] = f32_to_bf16(a.w);
        o.ush[4] = f32_to_bf16(b.x); o.ush[5] = f32_to_bf16(b.y);
        o.ush[6] = f32_to_bf16(b.z); o.ush[7] = f32_to_bf16(b.w);
        xb[i] = o.u4;
        return;
    }
    __shared__ __attribute__((aligned(16))) unsigned short row_s[M_DIM];  // 8 KB
    const int row = blockIdx.x;
    uint4* rs4 = (uint4*)row_s;
    rs4[tid]       = make_uint4(0u, 0u, 0u, 0u);
    rs4[tid + 256] = make_uint4(0u, 0u, 0u, 0u);
    __syncthreads();
    const size_t base = (size_t)row * NNZ_ROW;
    for (int j = tid; j < NNZ_ROW; j += 256) {
        const int c = cols[base + j];
        row_s[c] = f32_to_bf16(wval[base + j]);
    }
    __syncthreads();
    uint4* dst = (uint4*)(wb + (size_t)row * M_DIM);
    dst[tid]       = rs4[tid];
    dst[tid + 256] = rs4[tid + 256];
}

// ---------------------------------------------------------------------------
// Stage one 128-row half-tile (128 rows x 64 k, bf16) for K-offset kt.
// 8 waves: wave w writes segments {2w, 2w+1} (8 rows, 1024 B each) at
// LINEAR dest (base + lane*16). Lane's slot: row r = seg*8 + (l>>3),
// chunk' = l&7; LDS(r,c') holds global chunk c' ^ (r&7) = (l&7) ^ (l>>3).
// ---------------------------------------------------------------------------
__device__ __forceinline__ void stage_half(
    const unsigned short* __restrict__ src,
    int grow0, int kt, unsigned short* dst, int w, int l) {
#pragma unroll
    for (int j = 0; j < 2; ++j) {
        const int seg = w * 2 + j;
        const int r   = seg * 8 + (l >> 3);
        const int cg  = (l >> 3) ^ (l & 7);
        load_lds16(src + (size_t)(grow0 + r) * M_DIM + kt + cg * 8,
                   dst + seg * 512);
    }
}

// ---------------------------------------------------------------------------
// One phase = (MA, KS). Reads this phase's A frags (4x ds_read_b128) and,
// iff RDB, the KS B frags (4x, persist across the MA pair). Stage per SK:
// 0 = A-half0+A-half1 of tile t+1 (4 loads), 1 = B-half0 (2),
// 2 = B-half1 (2), 3 = none + vmcnt(0) (newest stage >= 1 phase old).
// Then: barrier; setprio(1); 16 MFMA; setprio(0); barrier.
// Fragment addressing (proven R7): row = base + l15, chunk c = KS*4+(l>>4),
// stored at chunk' = c ^ (row&7) = c ^ (l&7).
// ---------------------------------------------------------------------------
template <int MA, int KS, bool RDB, int SK>
__device__ __forceinline__ void phase_op(
    const unsigned short* As_c, const unsigned short* Bs_c,
    unsigned short* As_n, unsigned short* Bs_n,
    const unsigned short* __restrict__ Xb, const unsigned short* __restrict__ Wb,
    int bm0, int bn0, int kn, bool do_stage,
    int wm, int wn, int w, int l,
    bf16x8 (&bfr)[4], f32x4 (&acc)[2][4][4]) {
    const int l15 = l & 15;
    const int lg  = l >> 4;
    const int lx  = l & 7;
    const int ck  = ((KS * 4 + lg) ^ lx) << 3;   // ushort offset within row

    const unsigned short* Ab = As_c + (wm * 128 + MA * 64 + l15) * 64;
    bf16x8 af[4];
#pragma unroll
    for (int mf = 0; mf < 4; ++mf)
        af[mf] = *(const bf16x8*)(Ab + mf * 1024 + ck);

    if constexpr (RDB) {
        const unsigned short* Bb = Bs_c + (wn * 64 + l15) * 64;
#pragma unroll
        for (int nf = 0; nf < 4; ++nf)
            bfr[nf] = *(const bf16x8*)(Bb + nf * 1024 + ck);
    }

    if (do_stage) {
        if constexpr (SK == 0) {
            stage_half(Xb, bm0,       kn, As_n,        w, l);
            stage_half(Xb, bm0 + 128, kn, As_n + 8192, w, l);
        }
        if constexpr (SK == 1) stage_half(Wb, bn0,       kn, Bs_n,        w, l);
        if constexpr (SK == 2) stage_half(Wb, bn0 + 128, kn, Bs_n + 8192, w, l);
    }
    if constexpr (SK == 3)
        __builtin_amdgcn_s_waitcnt(0x0F70);   // vmcnt(0); newest stage was
                                              // issued >= 1 phase ago
    __builtin_amdgcn_s_barrier();

    __builtin_amdgcn_s_setprio(1);
#pragma unroll
    for (int mf = 0; mf < 4; ++mf)
#pragma unroll
        for (int nf = 0; nf < 4; ++nf)
            acc[MA][mf][nf] = __builtin_amdgcn_mfma_f32_16x16x32_bf16(
                af[mf], bfr[nf], acc[MA][mf][nf], 0, 0, 0);
    __builtin_amdgcn_s_setprio(0);
    __builtin_amdgcn_s_barrier();
}

// ---- main GEMM: C[b,n] = sum_k Xb[b,k]*Wb[n,k] + bias[n] -------------------
__global__ __launch_bounds__(512, 2) void gemm_bt_bias(
    const unsigned short* __restrict__ Xb,   // [B][M] bf16 bits
    const unsigned short* __restrict__ Wb,   // [N][M] bf16 bits
    const float* __restrict__ bias,          // [N]
    float* __restrict__ out)                 // [B][N]
{
    // A: 256x64, B: 256x64, double-buffered = 128 KiB total
    __shared__ __attribute__((aligned(16))) unsigned short As0[16384];
    __shared__ __attribute__((aligned(16))) unsigned short Bs0[16384];
    __shared__ __attribute__((aligned(16))) unsigned short As1[16384];
    __shared__ __attribute__((aligned(16))) unsigned short Bs1[16384];

    const int tid = threadIdx.x;
    const int w   = tid >> 6;     // wave 0..7
    const int l   = tid & 63;
    const int wm  = w >> 2;       // 0..1  (128-row M slice)
    const int wn  = w & 3;        // 0..3  (64-col N slice)

    // bijective XCD swizzle (256 blocks, 8 XCDs, 32 contiguous per XCD)
    const int wg  = blockIdx.y * 16 + blockIdx.x;
    const int idx = ((wg & 7) << 5) | (wg >> 3);
    const int bm0 = (idx >> 4) * 256;   // batch rows
    const int bn0 = (idx & 15) * 256;   // N cols

    f32x4 acc[2][4][4];
#pragma unroll
    for (int a = 0; a < 2; ++a)
#pragma unroll
        for (int b = 0; b < 4; ++b)
#pragma unroll
            for (int c = 0; c < 4; ++c) acc[a][b][c] = (f32x4)0.0f;

    bf16x8 bfr[4];

    // ---- prologue: stage K-tile 0 fully into buf0, drain, barrier ----
    stage_half(Xb, bm0,       0, As0,        w, l);
    stage_half(Xb, bm0 + 128, 0, As0 + 8192, w, l);
    stage_half(Wb, bn0,       0, Bs0,        w, l);
    stage_half(Wb, bn0 + 128, 0, Bs0 + 8192, w, l);
    __builtin_amdgcn_s_waitcnt(0x0F70);   // vmcnt(0), cold start only
    __builtin_amdgcn_s_barrier();

#define TILE4(AC, BC, AN, BN, KN, DS)                                          \
    phase_op<0, 0, true , 0>(AC, BC, AN, BN, Xb, Wb, bm0, bn0, KN, DS,         \
                             wm, wn, w, l, bfr, acc);                          \
    phase_op<1, 0, false, 1>(AC, BC, AN, BN, Xb, Wb, bm0, bn0, KN, DS,         \
                             wm, wn, w, l, bfr, acc);                          \
    phase_op<0, 1, true , 2>(AC, BC, AN, BN, Xb, Wb, bm0, bn0, KN, DS,         \
                             wm, wn, w, l, bfr, acc);                          \
    phase_op<1, 1, false, 3>(AC, BC, AN, BN, Xb, Wb, bm0, bn0, KN, DS,         \
                             wm, wn, w, l, bfr, acc);

    // ---- main loop: 2 K-tiles per iteration (buffer ping-pong) ----
#pragma unroll 1
    for (int kt = 0; kt < M_DIM; kt += 128) {
        TILE4(As0, Bs0, As1, Bs1, kt + 64, true)
        TILE4(As1, Bs1, As0, Bs0, kt + 128, kt + 128 < M_DIM)
    }
#undef TILE4

    // ---- epilogue: D elem r of acc -> row = (l>>4)*4+r, col = l&15 ----
    const int l15 = l & 15;
    const int lg  = l >> 4;
#pragma unroll
    for (int nf = 0; nf < 4; ++nf) {
        const int col = bn0 + wn * 64 + nf * 16 + l15;
        const float bv = bias[col];
#pragma unroll
        for (int ma = 0; ma < 2; ++ma)
#pragma unroll
            for (int mf = 0; mf < 4; ++mf) {
                const int row0 = bm0 + wm * 128 + ma * 64 + mf * 16 + lg * 4;
#pragma unroll
                for (int r = 0; r < 4; ++r)
                    out[(size_t)(row0 + r) * N_DIM + col] =
                        acc[ma][mf][nf][r] + bv;
            }
    }
}

// ---------------------------------------------------------------------------

extern "C" void kernel_launch(void* const* d_in, const int* in_sizes, int n_in,
                              void* d_out, int out_size, void* d_ws, size_t ws_size,
                              hipStream_t stream) {
    const float* x       = (const float*)d_in[0];
    const float* wval    = (const float*)d_in[1];
    const float* bias    = (const float*)d_in[2];
    const int*   cols    = (const int*)d_in[4];
    float* out = (float*)d_out;

    // workspace: Wb [N*M bf16] (32 MiB) | Xb [B*M bf16] (32 MiB)
    unsigned short* Wb = (unsigned short*)d_ws;
    unsigned short* Xb = Wb + (size_t)N_DIM * M_DIM;

    // merged prologue: 4096 densify blocks + 8192 cvt blocks
    prep<<<dim3(N_DIM + (B_DIM * M_DIM) / 8 / 256), dim3(256), 0, stream>>>(
        wval, cols, Wb, (const float4*)x, (uint4*)Xb);
    gemm_bt_bias<<<dim3(N_DIM / 256, B_DIM / 256), dim3(512), 0, stream>>>(
        Xb, Wb, bias, out);
}